// Round 1
// baseline (337.578 us; speedup 1.0000x reference)
//
#include <hip/hip_runtime.h>

// Wavelet cascade (db4, 4 levels, circular) on [B=64, L=512, D=256] f32.
// Key insight: the dense [L,L] filter matrices are 8-tap dilated circular
// convolutions: filter[j][m, (m - 2^j i) mod L] = wav[i]. We read only the
// 8 taps per level per filter and do the whole 4-level cascade in LDS.
//
// Output: [B, 5, L, D] f32 = {w_0..w_3 (detail), v_3 (approx)}.

#define WL   512   // signal length
#define WD   256   // feature dim
#define WTD  32    // d-tile per workgroup
#define WNT  512   // threads per block (8 waves)
#define WELEMS (WL * WTD / WNT)   // 32 elements per thread

__global__ __launch_bounds__(WNT, 4)
void wavelet_cascade_kernel(const float* __restrict__ x,
                            const float* __restrict__ hfil,   // w_dec_filter [4,512,512]
                            const float* __restrict__ gfil,   // v_dec_filter [4,512,512]
                            float* __restrict__ out) {
    // 512 x 32 f32 signal tile = 64 KB LDS (2 WGs/CU)
    __shared__ float buf[WL * WTD];

    const int b  = (int)blockIdx.x >> 3;          // D/WTD = 8 tiles
    const int d0 = ((int)blockIdx.x & 7) * WTD;
    const int t  = (int)threadIdx.x;

    // ---- stage x[b, :, d0:d0+32] -> LDS (float4, coalesced) ----
    {
        const float4* src = reinterpret_cast<const float4*>(x + (size_t)b * WL * WD + d0);
        float4* dst = reinterpret_cast<float4*>(buf);
#pragma unroll
        for (int k = 0; k < (WL * WTD / 4) / WNT; ++k) {   // 8 iters
            const int idx = t + k * WNT;
            const int l = idx >> 3;          // 8 float4 per row
            const int q = idx & 7;
            dst[l * 8 + q] = src[l * 64 + q];   // row stride 256 f32 = 64 float4
        }
    }
    __syncthreads();

    const int dd = t & 31;        // lane -> d (coalesced stores, bank-conflict-free LDS)
    const int l0 = t >> 5;        // 0..15
    float* outB = out + (size_t)b * 5 * WL * WD + d0 + dd;

    float vreg[WELEMS];           // v values held in registers between barriers

#pragma unroll
    for (int j = 0; j < 4; ++j) {           // level (compile-time)
        // taps for this level: filter[j][0, (0 - 2^j i) mod L] = wav[i]
        float h[8], g[8];
#pragma unroll
        for (int i = 0; i < 8; ++i) {
            const int off = (WL - (i << j)) & (WL - 1);   // i=0 -> 0
            h[i] = hfil[j * WL * WL + off];
            g[i] = gfil[j * WL * WL + off];
        }

#pragma unroll
        for (int k = 0; k < WELEMS; ++k) {
            const int l = l0 + k * 16;
            float wa = 0.f, va = 0.f;
#pragma unroll
            for (int i = 0; i < 8; ++i) {
                // lanes 0..31 read consecutive dd in one row: banks 0..31,
                // 2 lanes/bank across wave64 -> conflict-free
                const float val = buf[((l - (i << j)) & (WL - 1)) * WTD + dd];
                wa = fmaf(h[i], val, wa);
                va = fmaf(g[i], val, va);
            }
            outB[((size_t)j * WL + l) * WD] = wa;          // detail band j
            if (j == 3) {
                outB[((size_t)4 * WL + l) * WD] = va;      // final approx v_3
            } else {
                vreg[k] = va;
            }
        }

        if (j < 3) {
            __syncthreads();   // all reads of buf done
#pragma unroll
            for (int k = 0; k < WELEMS; ++k) {
                buf[(l0 + k * 16) * WTD + dd] = vreg[k];
            }
            __syncthreads();   // buf now holds v_j
        }
    }
}

extern "C" void kernel_launch(void* const* d_in, const int* in_sizes, int n_in,
                              void* d_out, int out_size, void* d_ws, size_t ws_size,
                              hipStream_t stream) {
    const float* x    = (const float*)d_in[0];
    const float* wfil = (const float*)d_in[1];   // w_dec_filter (detail, hi-pass)
    const float* vfil = (const float*)d_in[2];   // v_dec_filter (approx, lo-pass)
    float* out = (float*)d_out;

    wavelet_cascade_kernel<<<dim3(64 * 8), dim3(WNT), 0, stream>>>(x, wfil, vfil, out);
}

// Round 4
// 191.649 us; speedup vs baseline: 1.7614x; 1.7614x over previous
//
#include <hip/hip_runtime.h>

// Wavelet cascade (db4, 4 levels, circular) on [B=64, L=512, D=256] f32.
// Sparse view: filter[j][m, (m - 2^j i) mod L] = wav[i]  -> 8-tap dilated
// circular convolution per level; full 4-level cascade done in LDS.
// Output: [B, 5, L, D] f32 = {w_0..w_3 (detail), v_3 (approx)}.
//
// vs round-1 (221 us, 552 MB HBM vs 202 MB ideal):
//  - grid decode b=blk&63, d0=(blk>>6)*32: the 8 d-tiles of one b share an
//    XCD (blk mod 8 == b mod 8) and are co-resident -> output-line fragments
//    coalesce in one L2 (round-1 showed 2.7x HBM traffic inflation).
//  - f4 (ext_vector_type) LDS/global everywhere; LDS row stride 40 floats
//    (160 B) makes the row x quad access a 2-way bank alias only (free, m136).
//  - nontemporal loads for x (read-once, keep L2 for write coalescing).
//    NOTE: __builtin_nontemporal_load needs a clang native vector type,
//    not HIP's float4 class -> use ext_vector_type(4) alias.

typedef float f4 __attribute__((ext_vector_type(4)));

#define WL  512   // signal length
#define WD  256   // feature dim
#define WTD 32    // d-tile per workgroup
#define WNT 512   // threads per block (8 waves)
#define PS  40    // padded LDS row stride in floats (160 B)

__global__ __launch_bounds__(WNT, 4)
void wavelet_cascade_kernel(const float* __restrict__ x,
                            const float* __restrict__ hfil,   // w_dec_filter [4,512,512]
                            const float* __restrict__ gfil,   // v_dec_filter [4,512,512]
                            float* __restrict__ out) {
    __shared__ float buf[WL * PS];   // 80 KB -> 2 blocks/CU (160 KiB exactly)

    const int blk = (int)blockIdx.x;
    const int b   = blk & 63;          // same-b tiles: blk mod 8 == b mod 8 -> same XCD
    const int d0  = (blk >> 6) * WTD;  // 0..7 tile
    const int t   = (int)threadIdx.x;

    // ---- stage x[b, :, d0:d0+32] -> LDS (16B, nontemporal, coalesced) ----
    {
        const f4* src = reinterpret_cast<const f4*>(x + (size_t)b * WL * WD + d0);
#pragma unroll
        for (int k = 0; k < 8; ++k) {
            const int idx = t + k * WNT;
            const int l = idx >> 3;          // 8 f4 per row
            const int q = idx & 7;
            f4 v = __builtin_nontemporal_load(&src[l * (WD / 4) + q]);
            *reinterpret_cast<f4*>(&buf[l * PS + q * 4]) = v;
        }
    }
    __syncthreads();

    const int q  = t & 7;         // f4-column within the 32-wide d-tile
    const int l0 = t >> 3;        // 0..63
    float* outB = out + (size_t)b * 5 * WL * WD + d0 + q * 4;

    f4 vreg[8];                   // v values held in registers between barriers

#pragma unroll
    for (int j = 0; j < 4; ++j) {           // level (compile-time)
        // taps: filter[j][0, (0 - 2^j i) mod L] = wav[i]
        float h[8], g[8];
#pragma unroll
        for (int i = 0; i < 8; ++i) {
            const int off = (WL - (i << j)) & (WL - 1);   // i=0 -> 0
            h[i] = hfil[j * WL * WL + off];
            g[i] = gfil[j * WL * WL + off];
        }

#pragma unroll
        for (int k = 0; k < 8; ++k) {
            const int l = l0 + k * 64;
            f4 wa = {0.f, 0.f, 0.f, 0.f};
            f4 va = {0.f, 0.f, 0.f, 0.f};
#pragma unroll
            for (int i = 0; i < 8; ++i) {
                const int row = (l - (i << j)) & (WL - 1);
                const f4 val = *reinterpret_cast<const f4*>(&buf[row * PS + q * 4]);
                wa += h[i] * val;    // vector fma
                va += g[i] * val;
            }
            *reinterpret_cast<f4*>(&outB[((size_t)j * WL + l) * WD]) = wa;
            if (j == 3) {
                *reinterpret_cast<f4*>(&outB[((size_t)4 * WL + l) * WD]) = va;
            } else {
                vreg[k] = va;
            }
        }

        if (j < 3) {
            __syncthreads();   // all reads of buf done
#pragma unroll
            for (int k = 0; k < 8; ++k) {
                *reinterpret_cast<f4*>(&buf[(l0 + k * 64) * PS + q * 4]) = vreg[k];
            }
            __syncthreads();   // buf now holds v_j
        }
    }
}

extern "C" void kernel_launch(void* const* d_in, const int* in_sizes, int n_in,
                              void* d_out, int out_size, void* d_ws, size_t ws_size,
                              hipStream_t stream) {
    const float* x    = (const float*)d_in[0];
    const float* wfil = (const float*)d_in[1];   // w_dec_filter (detail, hi-pass)
    const float* vfil = (const float*)d_in[2];   // v_dec_filter (approx, lo-pass)
    float* out = (float*)d_out;

    wavelet_cascade_kernel<<<dim3(64 * 8), dim3(WNT), 0, stream>>>(x, wfil, vfil, out);
}